// Round 7
// baseline (517.716 us; speedup 1.0000x reference)
//
#include <hip/hip_runtime.h>

#define M_TOTAL 8192
#define KDIM 1024
#define TASKS 20
#define SBUF 256

typedef __bf16 bf16x8 __attribute__((ext_vector_type(8)));
typedef float f32x4 __attribute__((ext_vector_type(4)));

__device__ __forceinline__ unsigned short f2bf(float f) {
  unsigned int x = __float_as_uint(f);
  x += 0x7fffU + ((x >> 16) & 1U);
  return (unsigned short)(x >> 16);
}

__device__ __forceinline__ void gload_lds16(const unsigned short* g, char* l) {
  __builtin_amdgcn_global_load_lds((const __attribute__((address_space(1))) void*)g,
                                   (__attribute__((address_space(3))) void*)l, 16, 0, 0);
}

#define FENCE() asm volatile("" ::: "memory")
#define BAR() do { FENCE(); __builtin_amdgcn_s_barrier(); FENCE(); } while (0)
#define LGKM0() asm volatile("s_waitcnt lgkmcnt(0)" ::: "memory")
#define VMC(n) asm volatile("s_waitcnt vmcnt(" #n ")" ::: "memory")
#define SCHED0() __builtin_amdgcn_sched_barrier(0)
#define MFMA_(a, bb, c) (c) = __builtin_amdgcn_mfma_f32_16x16x32_bf16((a), (bb), (c), 0, 0, 0)

// One block per row: L2-normalize a 1024-float row of X or W, emit bf16.
__global__ __launch_bounds__(256) void norm_rows_kernel(const float* __restrict__ X,
                                                        const float* __restrict__ W,
                                                        unsigned short* __restrict__ Xn,
                                                        unsigned short* __restrict__ Wn) {
  const int row = blockIdx.x;
  const int tid = threadIdx.x;
  const float* in;
  unsigned short* outp;
  int r;
  if (row < M_TOTAL) { in = X; outp = Xn; r = row; }
  else               { in = W; outp = Wn; r = row - M_TOTAL; }
  const float4 v = ((const float4*)(in + (size_t)r * KDIM))[tid];
  float s = v.x * v.x + v.y * v.y + v.z * v.z + v.w * v.w;
#pragma unroll
  for (int off = 32; off >= 1; off >>= 1) s += __shfl_xor(s, off, 64);
  __shared__ float part[4];
  if ((tid & 63) == 0) part[tid >> 6] = s;
  __syncthreads();
  s = part[0] + part[1] + part[2] + part[3];
  const float sc = rsqrtf(s);
  ushort4 o;
  o.x = f2bf(v.x * sc);
  o.y = f2bf(v.y * sc);
  o.z = f2bf(v.z * sc);
  o.w = f2bf(v.w * sc);
  ((ushort4*)(outp + (size_t)r * KDIM))[tid] = o;
}

// 128(M) x 256(N = one full task) tile, BK=32. 256 thr = 4 waves (2M x 2N),
// wave tile 64x128: acc[4][8] (128 AGPR), 12 ds_read_b128 : 32 MFMA per K-tile.
// 3 blocks/CU (150528 B LDS total): three independent barrier domains per CU
// drift out of phase and cover each other's lgkm/vmcnt/barrier stalls —
// rounds 3 & 6 both pinned at 40% MfmaUtil with only 2 domains.
// LDS (bytes): A bufs [0,16K) 2x8K; B bufs [16K,48K) 2x16K; red [48K,49K)
// wait: red is at 49152 (OUTSIDE all staging destinations — round-5 race).
// Pair-row swizzle: rows 2q,2q+1 share a 128B block; granule(row,s) =
// (((row&1)<<2)|s) ^ (q&7). Stage dest is linear (granule g -> byte g*16,
// g = chunk*256+tid); the global SOURCE is inverse-permuted (rule #21).
__global__ __launch_bounds__(256, 3) void gemm_min_kernel(const unsigned short* __restrict__ Xn,
                                                          const unsigned short* __restrict__ Wn,
                                                          float* __restrict__ out) {
  __shared__ __align__(16) char sm[50176];

  const int tid = threadIdx.x;
  const int lane = tid & 63;
  const int w = tid >> 6, wr = w >> 1, wc = w & 1;
  const int lrow = lane & 15, lgrp = lane >> 4;

  // XCD swizzle: 1280 blocks; xcd owns an 8-mblk stripe, mblk fastest, task slow.
  const int o = blockIdx.x;
  const int xcd = o & 7, i = o >> 3;        // i in [0,160)
  const int task = i >> 3;                   // 0..19
  const int mblk = xcd * 8 + (i & 7);        // 0..63
  const int rowBase = mblk * 128;
  const int col0 = task * SBUF;

  // staging source decode (inverse pair-row swizzle); chunk c adds 64 rows
  // (c*64*KDIM on the source, c*4096 on the linear LDS dest) — s8 is chunk-invariant.
  const int s8 = (tid & 7) ^ ((tid >> 3) & 7);
  const int rowl = 2 * (tid >> 3) + (s8 >> 2);   // 0..63
  const int koff = (s8 & 3) * 8;
  const unsigned short* pA = Xn + (size_t)(rowBase + rowl) * KDIM + koff;
  const unsigned short* pB = Wn + (size_t)(col0 + rowl) * KDIM + koff;
  char* const sdA = sm + tid * 16;
  char* const sdB = sm + 16384 + tid * 16;

  // ds_read lane bases (frag row base is a multiple of 16 -> (row>>1)&7 = lrow>>1)
  const int gran = ((((lrow & 1) << 2) | lgrp) ^ (lrow >> 1)) * 16;
  const int aBase = wr * 4096 + (lrow >> 1) * 128 + gran;            // + B_*8192
  const int bBase = 16384 + wc * 8192 + (lrow >> 1) * 128 + gran;    // + B_*16384

  f32x4 acc[4][8] = {};

  // 6 loads/thread/K-tile: A chunks c=0..1 (128 rows), B chunks c=0..3 (256 rows)
#define STG(B_, kSt) do { \
    gload_lds16(pA + (kSt), sdA + (B_) * 8192); \
    gload_lds16(pA + 64 * KDIM + (kSt), sdA + (B_) * 8192 + 4096); \
    gload_lds16(pB + (kSt), sdB + (B_) * 16384); \
    gload_lds16(pB + 64 * KDIM + (kSt), sdB + (B_) * 16384 + 4096); \
    gload_lds16(pB + 128 * KDIM + (kSt), sdB + (B_) * 16384 + 8192); \
    gload_lds16(pB + 192 * KDIM + (kSt), sdB + (B_) * 16384 + 12288); \
  } while (0)

  // prologue: tile0 -> buf0, tile1 -> buf1; drain tile0 (6 of 12), tile1 in flight
  STG(0, 0);
  STG(1, 32);
  VMC(6); SCHED0();
  BAR();

  // Per K-tile: Ph1 {12 ds_read, MFMA n0..3, lgkm-drain, BAR};
  //             Ph2 {stage t+2 -> own buf, VMC(6) [t+1 resident], MFMA n4..7, BAR}.
#define KTILE(B_, kt) do { \
    bf16x8 aF[4], bF[8]; \
    const char* ab = sm + (B_) * 8192 + aBase; \
    const char* bb = sm + (B_) * 16384 + bBase; \
    _Pragma("unroll") for (int m = 0; m < 4; ++m) aF[m] = *(const bf16x8*)(ab + m * 1024); \
    _Pragma("unroll") for (int n = 0; n < 8; ++n) bF[n] = *(const bf16x8*)(bb + n * 1024); \
    __builtin_amdgcn_s_setprio(1); \
    _Pragma("unroll") for (int m = 0; m < 4; ++m) \
      _Pragma("unroll") for (int n = 0; n < 4; ++n) MFMA_(aF[m], bF[n], acc[m][n]); \
    __builtin_amdgcn_s_setprio(0); \
    LGKM0(); SCHED0(); \
    BAR(); \
    { const int kSt = ((kt) + 2 < 32) ? ((kt) + 2) * 32 : 0; STG(B_, kSt); } \
    VMC(6); SCHED0(); \
    __builtin_amdgcn_s_setprio(1); \
    _Pragma("unroll") for (int m = 0; m < 4; ++m) \
      _Pragma("unroll") for (int n = 4; n < 8; ++n) MFMA_(aF[m], bF[n], acc[m][n]); \
    __builtin_amdgcn_s_setprio(0); \
    BAR(); \
  } while (0)

  for (int kt = 0; kt < 32; kt += 2) {
    KTILE(0, kt);
    KTILE(1, kt + 1);
  }

  // Drain the wrap-garbage stages before touching LDS again / ending the block:
  // in-flight global_load_lds DMAs would otherwise land after red is written
  // (or after LDS is reallocated to a successor block).
  VMC(0); SCHED0();
  BAR();

  // epilogue: per-row max-dot over 8 n-frags + 16 col-lanes -> red -> store
  float (*red)[2] = (float (*)[2])(sm + 49152);  // [128][2], outside staging regions
#pragma unroll
  for (int m = 0; m < 4; ++m) {
#pragma unroll
    for (int rr = 0; rr < 4; ++rr) {
      float v = -1e30f;
#pragma unroll
      for (int n = 0; n < 8; ++n) v = fmaxf(v, acc[m][n][rr]);
      v = fmaxf(v, __shfl_xor(v, 1, 64));
      v = fmaxf(v, __shfl_xor(v, 2, 64));
      v = fmaxf(v, __shfl_xor(v, 4, 64));
      v = fmaxf(v, __shfl_xor(v, 8, 64));
      if (lrow == 0) red[wr * 64 + m * 16 + lgrp * 4 + rr][wc] = v;
    }
  }
  BAR();
  if (tid < 128) {
    const float vv = fmaxf(red[tid][0], red[tid][1]);
    const float d = sqrtf(fmaxf(2.0f - 2.0f * vv, 1e-12f));
    out[(size_t)(rowBase + tid) * TASKS + task] = -d;
  }
#undef KTILE
#undef STG
}

extern "C" void kernel_launch(void* const* d_in, const int* in_sizes, int n_in,
                              void* d_out, int out_size, void* d_ws, size_t ws_size,
                              hipStream_t stream) {
  const float* X = (const float*)d_in[0];   // (8192, 1024) fp32
  const float* W = (const float*)d_in[1];   // (5120, 1024) fp32
  float* out = (float*)d_out;               // (8192, 20) fp32

  unsigned short* Xn = (unsigned short*)d_ws;
  unsigned short* Wn = (unsigned short*)((char*)d_ws + (size_t)M_TOTAL * KDIM * 2);

  norm_rows_kernel<<<M_TOTAL + TASKS * SBUF, 256, 0, stream>>>(X, W, Xn, Wn);
  gemm_min_kernel<<<1280, 256, 0, stream>>>(Xn, Wn, out);
}

// Round 8
// 117.218 us; speedup vs baseline: 4.4167x; 4.4167x over previous
//
#include <hip/hip_runtime.h>

#define M_TOTAL 8192
#define KDIM 1024
#define TASKS 20
#define SBUF 256

typedef __bf16 bf16x8 __attribute__((ext_vector_type(8)));
typedef float f32x4 __attribute__((ext_vector_type(4)));

__device__ __forceinline__ unsigned short f2bf(float f) {
  unsigned int x = __float_as_uint(f);
  x += 0x7fffU + ((x >> 16) & 1U);
  return (unsigned short)(x >> 16);
}

__device__ __forceinline__ void gload_lds16(const unsigned short* g, char* l) {
  __builtin_amdgcn_global_load_lds((const __attribute__((address_space(1))) void*)g,
                                   (__attribute__((address_space(3))) void*)l, 16, 0, 0);
}

#define FENCE() asm volatile("" ::: "memory")
#define BAR() do { FENCE(); __builtin_amdgcn_s_barrier(); FENCE(); } while (0)
#define LGKM0() asm volatile("s_waitcnt lgkmcnt(0)" ::: "memory")
#define VMC(n) asm volatile("s_waitcnt vmcnt(" #n ")" ::: "memory")
#define SCHED0() __builtin_amdgcn_sched_barrier(0)
#define MFMA_(a, bb, c) (c) = __builtin_amdgcn_mfma_f32_16x16x32_bf16((a), (bb), (c), 0, 0, 0)

// One block per row: L2-normalize a 1024-float row of X or W, emit bf16.
// First 640 blocks also init out[] to -1e30 (uint-max for the atomicMin combine);
// stream order guarantees this completes before the gemm kernel's atomics.
__global__ __launch_bounds__(256) void norm_rows_kernel(const float* __restrict__ X,
                                                        const float* __restrict__ W,
                                                        unsigned short* __restrict__ Xn,
                                                        unsigned short* __restrict__ Wn,
                                                        float* __restrict__ out) {
  const int row = blockIdx.x;
  const int tid = threadIdx.x;
  if (row < (M_TOTAL * TASKS) / 256) out[row * 256 + tid] = -1e30f;
  const float* in;
  unsigned short* outp;
  int r;
  if (row < M_TOTAL) { in = X; outp = Xn; r = row; }
  else               { in = W; outp = Wn; r = row - M_TOTAL; }
  const float4 v = ((const float4*)(in + (size_t)r * KDIM))[tid];
  float s = v.x * v.x + v.y * v.y + v.z * v.z + v.w * v.w;
#pragma unroll
  for (int off = 32; off >= 1; off >>= 1) s += __shfl_xor(s, off, 64);
  __shared__ float part[4];
  if ((tid & 63) == 0) part[tid >> 6] = s;
  __syncthreads();
  s = part[0] + part[1] + part[2] + part[3];
  const float sc = rsqrtf(s);
  ushort4 o;
  o.x = f2bf(v.x * sc);
  o.y = f2bf(v.y * sc);
  o.z = f2bf(v.z * sc);
  o.w = f2bf(v.w * sc);
  ((ushort4*)(outp + (size_t)r * KDIM))[tid] = o;
}

// 128(M) x 128(N = half task) tile, BK=32. 256 thr = 4 waves (2M x 2N),
// wave tile 64x64: acc[4][4] (64 acc + ~60 arch ~= 124 regs) -> fits 3-4
// blocks/CU (per-SIMD unified pool is 512 wave-regs: r3 124@cap128 ok,
// r4/r7 spilled past it). 3+ independent barrier domains per CU cover each
// other's lgkm/vmcnt/barrier stalls (r3 & r6 both pinned at 40% with 2).
// LDS (bytes): A bufs [0,16K) 2x8K; B bufs [16K,32K) 2x8K; red [32K,33K).
// Pair-row swizzle: rows 2q,2q+1 share a 128B block; granule(row,s) =
// (((row&1)<<2)|s) ^ (q&7). Stage dest is linear (granule g -> byte g*16,
// g = chunk*256+tid); the global SOURCE is inverse-permuted (rule #21).
// Half-task min combined across 2 blocks via uint atomicMin on negative floats
// (exact, order-independent; float max == -min dist).
__global__ __launch_bounds__(256, 3) void gemm_min_kernel(const unsigned short* __restrict__ Xn,
                                                          const unsigned short* __restrict__ Wn,
                                                          float* __restrict__ out) {
  __shared__ __align__(16) char sm[33792];

  const int tid = threadIdx.x;
  const int lane = tid & 63;
  const int w = tid >> 6, wr = w >> 1, wc = w & 1;
  const int lrow = lane & 15, lgrp = lane >> 4;

  // XCD swizzle: 2560 blocks; xcd owns an 8-mblk stripe, mblk fastest ->
  // 8 consecutive blocks share one 0.25MB B-half in L2; nblk slow.
  const int o = blockIdx.x;
  const int xcd = o & 7, i = o >> 3;        // i in [0,320)
  const int nblk = i >> 3;                   // 0..39
  const int mblk = xcd * 8 + (i & 7);        // 0..63
  const int rowBase = mblk * 128;
  const int col0 = nblk * 128;               // W row base
  const int task = nblk >> 1;

  // staging source decode (inverse pair-row swizzle); chunk c adds 64 rows
  // (c*64*KDIM source, c*4096 linear LDS dest) — s8 is chunk-invariant.
  const int s8 = (tid & 7) ^ ((tid >> 3) & 7);
  const int rowl = 2 * (tid >> 3) + (s8 >> 2);   // 0..63
  const int koff = (s8 & 3) * 8;
  const unsigned short* pA = Xn + (size_t)(rowBase + rowl) * KDIM + koff;
  const unsigned short* pB = Wn + (size_t)(col0 + rowl) * KDIM + koff;
  char* const sdA = sm + tid * 16;
  char* const sdB = sm + 16384 + tid * 16;

  // ds_read lane bases (frag row base is a multiple of 16 -> (row>>1)&7 = lrow>>1)
  const int gran = ((((lrow & 1) << 2) | lgrp) ^ (lrow >> 1)) * 16;
  const int aBase = wr * 4096 + (lrow >> 1) * 128 + gran;            // + B_*8192
  const int bBase = 16384 + wc * 4096 + (lrow >> 1) * 128 + gran;    // + B_*8192

  f32x4 acc[4][4] = {};

  // 4 loads/thread/K-tile: A chunks c=0..1 (128 rows), B chunks c=0..1 (128 rows)
#define STG(B_, kSt) do { \
    gload_lds16(pA + (kSt), sdA + (B_) * 8192); \
    gload_lds16(pA + 64 * KDIM + (kSt), sdA + (B_) * 8192 + 4096); \
    gload_lds16(pB + (kSt), sdB + (B_) * 8192); \
    gload_lds16(pB + 64 * KDIM + (kSt), sdB + (B_) * 8192 + 4096); \
  } while (0)

  // prologue: tile0 -> buf0, tile1 -> buf1; drain tile0 (4 of 8), tile1 in flight
  STG(0, 0);
  STG(1, 32);
  VMC(4); SCHED0();
  BAR();

  // Per K-tile: Ph1 {8 ds_read, MFMA n0..1, lgkm-drain, BAR};
  //             Ph2 {stage t+2 -> own buf, VMC(4) [t+1 resident], MFMA n2..3, BAR}.
#define KTILE(B_, kt) do { \
    bf16x8 aF[4], bF[4]; \
    const char* ab = sm + (B_) * 8192 + aBase; \
    const char* bb = sm + (B_) * 8192 + bBase; \
    _Pragma("unroll") for (int m = 0; m < 4; ++m) aF[m] = *(const bf16x8*)(ab + m * 1024); \
    _Pragma("unroll") for (int n = 0; n < 4; ++n) bF[n] = *(const bf16x8*)(bb + n * 1024); \
    __builtin_amdgcn_s_setprio(1); \
    _Pragma("unroll") for (int m = 0; m < 4; ++m) { MFMA_(aF[m], bF[0], acc[m][0]); MFMA_(aF[m], bF[1], acc[m][1]); } \
    __builtin_amdgcn_s_setprio(0); \
    LGKM0(); SCHED0(); \
    BAR(); \
    { const int kSt = ((kt) + 2 < 32) ? ((kt) + 2) * 32 : 0; STG(B_, kSt); } \
    VMC(4); SCHED0(); \
    __builtin_amdgcn_s_setprio(1); \
    _Pragma("unroll") for (int m = 0; m < 4; ++m) { MFMA_(aF[m], bF[2], acc[m][2]); MFMA_(aF[m], bF[3], acc[m][3]); } \
    __builtin_amdgcn_s_setprio(0); \
    BAR(); \
  } while (0)

  for (int kt = 0; kt < 32; kt += 2) {
    KTILE(0, kt);
    KTILE(1, kt + 1);
  }

  // Drain wrap-garbage stages before reusing LDS / ending the block (r5 race).
  VMC(0); SCHED0();
  BAR();

  // epilogue: per-row max-dot over 4 n-frags + 16 col-lanes -> red -> atomic
  float (*red)[2] = (float (*)[2])(sm + 32768);  // [128][2], outside staging regions
#pragma unroll
  for (int m = 0; m < 4; ++m) {
#pragma unroll
    for (int rr = 0; rr < 4; ++rr) {
      float v = fmaxf(fmaxf(acc[m][0][rr], acc[m][1][rr]), fmaxf(acc[m][2][rr], acc[m][3][rr]));
      v = fmaxf(v, __shfl_xor(v, 1, 64));
      v = fmaxf(v, __shfl_xor(v, 2, 64));
      v = fmaxf(v, __shfl_xor(v, 4, 64));
      v = fmaxf(v, __shfl_xor(v, 8, 64));
      if (lrow == 0) red[wr * 64 + m * 16 + lgrp * 4 + rr][wc] = v;
    }
  }
  BAR();
  if (tid < 128) {
    const float vv = fmaxf(red[tid][0], red[tid][1]);
    const float d = sqrtf(fmaxf(2.0f - 2.0f * vv, 1e-12f));
    // all published values negative: uint atomicMin == float max == -min dist
    atomicMin((unsigned int*)&out[(size_t)(rowBase + tid) * TASKS + task],
              __float_as_uint(-d));
  }
#undef KTILE
#undef STG
}

extern "C" void kernel_launch(void* const* d_in, const int* in_sizes, int n_in,
                              void* d_out, int out_size, void* d_ws, size_t ws_size,
                              hipStream_t stream) {
  const float* X = (const float*)d_in[0];   // (8192, 1024) fp32
  const float* W = (const float*)d_in[1];   // (5120, 1024) fp32
  float* out = (float*)d_out;               // (8192, 20) fp32

  unsigned short* Xn = (unsigned short*)d_ws;
  unsigned short* Wn = (unsigned short*)((char*)d_ws + (size_t)M_TOTAL * KDIM * 2);

  norm_rows_kernel<<<M_TOTAL + TASKS * SBUF, 256, 0, stream>>>(X, W, Xn, Wn, out);
  gemm_min_kernel<<<2560, 256, 0, stream>>>(Xn, Wn, out);
}

// Round 9
// 102.112 us; speedup vs baseline: 5.0701x; 1.1479x over previous
//
#include <hip/hip_runtime.h>

#define M_TOTAL 8192
#define KDIM 1024
#define TASKS 20
#define SBUF 256

typedef __bf16 bf16x8 __attribute__((ext_vector_type(8)));
typedef float f32x4 __attribute__((ext_vector_type(4)));

__device__ __forceinline__ unsigned short f2bf(float f) {
  unsigned int x = __float_as_uint(f);
  x += 0x7fffU + ((x >> 16) & 1U);
  return (unsigned short)(x >> 16);
}

__device__ __forceinline__ void gload_lds16(const unsigned short* g, char* l) {
  __builtin_amdgcn_global_load_lds((const __attribute__((address_space(1))) void*)g,
                                   (__attribute__((address_space(3))) void*)l, 16, 0, 0);
}

#define FENCE() asm volatile("" ::: "memory")
#define BAR() do { FENCE(); __builtin_amdgcn_s_barrier(); FENCE(); } while (0)
#define VMC(n) asm volatile("s_waitcnt vmcnt(" #n ")" ::: "memory")
#define SCHED0() __builtin_amdgcn_sched_barrier(0)
#define MFMA_(a, bb, c) (c) = __builtin_amdgcn_mfma_f32_16x16x32_bf16((a), (bb), (c), 0, 0, 0)

// One block per row: L2-normalize a 1024-float row of X or W, emit bf16.
__global__ __launch_bounds__(256) void norm_rows_kernel(const float* __restrict__ X,
                                                        const float* __restrict__ W,
                                                        unsigned short* __restrict__ Xn,
                                                        unsigned short* __restrict__ Wn) {
  const int row = blockIdx.x;
  const int tid = threadIdx.x;
  const float* in;
  unsigned short* outp;
  int r;
  if (row < M_TOTAL) { in = X; outp = Xn; r = row; }
  else               { in = W; outp = Wn; r = row - M_TOTAL; }
  const float4 v = ((const float4*)(in + (size_t)r * KDIM))[tid];
  float s = v.x * v.x + v.y * v.y + v.z * v.z + v.w * v.w;
#pragma unroll
  for (int off = 32; off >= 1; off >>= 1) s += __shfl_xor(s, off, 64);
  __shared__ float part[4];
  if ((tid & 63) == 0) part[tid >> 6] = s;
  __syncthreads();
  s = part[0] + part[1] + part[2] + part[3];
  const float sc = rsqrtf(s);
  ushort4 o;
  o.x = f2bf(v.x * sc);
  o.y = f2bf(v.y * sc);
  o.z = f2bf(v.z * sc);
  o.w = f2bf(v.w * sc);
  ((ushort4*)(outp + (size_t)r * KDIM))[tid] = o;
}

// 128(M) x 256(N = one full task) tile, BK=32. 256 thr = 4 waves (2M x 2N),
// wave tile 64x128: acc[4][8], 12 ds_read_b128 : 32 MFMA per K-tile.
// *** 3-buffer rotation, ONE barrier per K-tile ***: tile t reads buf t%3,
// stages tile t+2 into buf (t+2)%3 — never a buffer being read by tile t or
// t+1, so the LGKM0-drain + extra barrier of the 2-buffer scheme vanish.
// Every ds_read is MFMA-consumed before the tile-end barrier, so passing the
// barrier implies reads done (no read/overwrite race). Ledger: at tile end,
// outstanding <= 12 loads; VMC(6) waits exactly for tile t+1's 6 loads; the
// following barrier makes all waves' slices globally resident.
// 2 blocks/CU (LDS 73 KB, regs ~232 <= 256 cap at 2 waves/SIMD — r3/r7
// calibration: per-SIMD unified pool is 512 wave-regs).
// LDS (bytes): buf b at b*24576: A [0,8K), B [8K,24K); red at [73728,74752).
// Pair-row swizzle: rows 2q,2q+1 share a 128B block; granule(row,s) =
// (((row&1)<<2)|s) ^ (q&7). Stage dest is linear (granule g -> byte g*16,
// g = chunk*256+tid); the global SOURCE is inverse-permuted (rule #21).
__global__ __launch_bounds__(256, 2) void gemm_min_kernel(const unsigned short* __restrict__ Xn,
                                                          const unsigned short* __restrict__ Wn,
                                                          float* __restrict__ out) {
  __shared__ __align__(16) char sm[74752];

  const int tid = threadIdx.x;
  const int lane = tid & 63;
  const int w = tid >> 6, wr = w >> 1, wc = w & 1;
  const int lrow = lane & 15, lgrp = lane >> 4;

  // XCD swizzle: 1280 blocks; xcd owns an 8-mblk stripe, mblk fastest, task slow.
  const int o = blockIdx.x;
  const int xcd = o & 7, i = o >> 3;        // i in [0,160)
  const int task = i >> 3;                   // 0..19
  const int mblk = xcd * 8 + (i & 7);        // 0..63
  const int rowBase = mblk * 128;
  const int col0 = task * SBUF;

  // staging source decode (inverse pair-row swizzle); chunk c adds 64 rows
  // (c*64*KDIM source, c*4096 linear LDS dest) — s8 is chunk-invariant.
  const int s8 = (tid & 7) ^ ((tid >> 3) & 7);
  const int rowl = 2 * (tid >> 3) + (s8 >> 2);   // 0..63
  const int koff = (s8 & 3) * 8;
  const unsigned short* pA = Xn + (size_t)(rowBase + rowl) * KDIM + koff;
  const unsigned short* pB = Wn + (size_t)(col0 + rowl) * KDIM + koff;

  // ds_read lane bases, buffer-relative (frag row base mult of 16 -> (row>>1)&7 = lrow>>1)
  const int gran = ((((lrow & 1) << 2) | lgrp) ^ (lrow >> 1)) * 16;
  const int aBase = wr * 4096 + (lrow >> 1) * 128 + gran;
  const int bBase = 8192 + wc * 8192 + (lrow >> 1) * 128 + gran;

  f32x4 acc[4][8] = {};

  // 6 loads/thread/K-tile into buf BUF: A chunks 0..1, B chunks 0..3
#define STG(BUF, kSt) do { \
    char* db = sm + (BUF) * 24576 + tid * 16; \
    gload_lds16(pA + (kSt), db); \
    gload_lds16(pA + 64 * KDIM + (kSt), db + 4096); \
    gload_lds16(pB + (kSt), db + 8192); \
    gload_lds16(pB + 64 * KDIM + (kSt), db + 12288); \
    gload_lds16(pB + 128 * KDIM + (kSt), db + 16384); \
    gload_lds16(pB + 192 * KDIM + (kSt), db + 20480); \
  } while (0)

  // prologue: tile0 -> buf0, tile1 -> buf1; VMC(6) -> tile0 resident
  STG(0, 0);
  STG(1, 32);
  VMC(6); SCHED0();
  BAR();

  // Per K-tile t (buf B_ = t%3): {12 ds_read; stage t+2 -> buf (B_+2)%3;
  //  32 MFMA (implicit counted lgkm waits); VMC(6) [t+1 resident]; BAR}.
#define KTILE(B_, kt) do { \
    bf16x8 aF[4], bF[8]; \
    const char* ab = sm + (B_) * 24576 + aBase; \
    const char* bb = sm + (B_) * 24576 + bBase; \
    _Pragma("unroll") for (int m = 0; m < 4; ++m) aF[m] = *(const bf16x8*)(ab + m * 1024); \
    _Pragma("unroll") for (int n = 0; n < 8; ++n) bF[n] = *(const bf16x8*)(bb + n * 1024); \
    { const int kSt = ((kt) + 2 < 32) ? ((kt) + 2) * 32 : 0; STG(((B_) + 2) % 3, kSt); } \
    SCHED0(); \
    __builtin_amdgcn_s_setprio(1); \
    _Pragma("unroll") for (int m = 0; m < 4; ++m) \
      _Pragma("unroll") for (int n = 0; n < 8; ++n) MFMA_(aF[m], bF[n], acc[m][n]); \
    __builtin_amdgcn_s_setprio(0); \
    VMC(6); SCHED0(); \
    BAR(); \
  } while (0)

  for (int kt = 0; kt < 30; kt += 3) {
    KTILE(0, kt);
    KTILE(1, kt + 1);
    KTILE(2, kt + 2);
  }
  KTILE(0, 30);
  KTILE(1, 31);

  // Drain wrap-garbage stages before reusing LDS / ending the block (r5 race).
  VMC(0); SCHED0();
  BAR();

  // epilogue: per-row max-dot over 8 n-frags + 16 col-lanes -> red -> store
  float (*red)[2] = (float (*)[2])(sm + 73728);  // outside all staging regions
#pragma unroll
  for (int m = 0; m < 4; ++m) {
#pragma unroll
    for (int rr = 0; rr < 4; ++rr) {
      float v = -1e30f;
#pragma unroll
      for (int n = 0; n < 8; ++n) v = fmaxf(v, acc[m][n][rr]);
      v = fmaxf(v, __shfl_xor(v, 1, 64));
      v = fmaxf(v, __shfl_xor(v, 2, 64));
      v = fmaxf(v, __shfl_xor(v, 4, 64));
      v = fmaxf(v, __shfl_xor(v, 8, 64));
      if (lrow == 0) red[wr * 64 + m * 16 + lgrp * 4 + rr][wc] = v;
    }
  }
  BAR();
  if (tid < 128) {
    const float vv = fmaxf(red[tid][0], red[tid][1]);
    const float d = sqrtf(fmaxf(2.0f - 2.0f * vv, 1e-12f));
    out[(size_t)(rowBase + tid) * TASKS + task] = -d;
  }
#undef KTILE
#undef STG
}

extern "C" void kernel_launch(void* const* d_in, const int* in_sizes, int n_in,
                              void* d_out, int out_size, void* d_ws, size_t ws_size,
                              hipStream_t stream) {
  const float* X = (const float*)d_in[0];   // (8192, 1024) fp32
  const float* W = (const float*)d_in[1];   // (5120, 1024) fp32
  float* out = (float*)d_out;               // (8192, 20) fp32

  unsigned short* Xn = (unsigned short*)d_ws;
  unsigned short* Wn = (unsigned short*)((char*)d_ws + (size_t)M_TOTAL * KDIM * 2);

  norm_rows_kernel<<<M_TOTAL + TASKS * SBUF, 256, 0, stream>>>(X, W, Xn, Wn);
  gemm_min_kernel<<<1280, 256, 0, stream>>>(Xn, Wn, out);
}